// Round 1
// baseline (1597.511 us; speedup 1.0000x reference)
//
#include <hip/hip_runtime.h>

#define BATCH    8192
#define V        512
#define C        16
#define N1       513
#define KCH      16     // variables per chunk
#define NCHUNKS  32
#define RB       32     // batch rows per block
#define NTHREADS 512
#define PTS      32     // Pt row stride (floats); stride 32 -> row n covers all 32 banks
#define DGS      512    // Dg row stride (floats)

// Thread mapping (GEMM / phase-2):
//   tid = rg + 8*jg,  jg = ch + 2*mat + 4*vlo
//   rg:  row group (4 rows each)        -> rows r0..r0+3 of the 32-row tile
//   jg:  8 output columns j0..j0+7, j = jg*8+jj, c = ch*8+jj, mat = pos/neg
//   vlo: which step of the chunk this thread's accumulators belong to
__global__ __launch_bounds__(NTHREADS, 1)
void shield_kernel(const float* __restrict__ preds,
                   const float* __restrict__ pos_mats,
                   const float* __restrict__ neg_mats,
                   float* __restrict__ out)
{
    __shared__ float Pt[N1 * PTS];     // transposed P tile: Pt[n][r], 65.7 KB
    __shared__ float Dg[(KCH + 1) * DGS]; // chunk diagonal block + bias row, 34.8 KB

    const int tid = threadIdx.x;
    const int b0  = blockIdx.x * RB;

    const int rg  = tid & 7;
    const int jg  = tid >> 3;
    const int ch  = jg & 1;
    const int mat = (jg >> 1) & 1;
    const int vlo = jg >> 2;
    const int r0  = rg * 4;
    const int c0  = ch * 8;
    const int j0  = jg * 8;

    // ---- load P tile, transposed into LDS ----
    {
        const int r = tid >> 4, seg = tid & 15;
        const float* prow = preds + (size_t)(b0 + r) * V + seg * 32;
        #pragma unroll
        for (int k = 0; k < 32; k += 4) {
            const float4 p4 = *(const float4*)(prow + k);
            const int n = seg * 32 + k;
            Pt[(n + 0) * PTS + r] = p4.x;
            Pt[(n + 1) * PTS + r] = p4.y;
            Pt[(n + 2) * PTS + r] = p4.z;
            Pt[(n + 3) * PTS + r] = p4.w;
        }
        if (tid < RB) Pt[V * PTS + tid] = 1.0f;   // bias row (column 512) = 1
    }

    const float* Mbase = mat ? neg_mats : pos_mats;
    float acc[8][4];

    #pragma unroll 1
    for (int chunk = 0; chunk < NCHUNKS; ++chunk) {
        const int v0 = chunk * KCH;
        __syncthreads();   // Pt rows of prev chunk final; Dg free for restage

        // ---- stage diagonal block: Dg[np][j] = M[v0+vl][c][v0+np], np=KCH -> bias ----
        {
            const int jj2  = tid & 7;
            const int ch2  = (tid >> 3) & 1;
            const int mat2 = (tid >> 4) & 1;
            const int vl2  = tid >> 5;
            const float* row = (mat2 ? neg_mats : pos_mats)
                             + (size_t)((v0 + vl2) * C + ch2 * 8 + jj2) * N1;
            #pragma unroll
            for (int np = 0; np < KCH; ++np)
                Dg[np * DGS + tid] = row[v0 + np];
            Dg[KCH * DGS + tid] = row[V];   // bias column
        }
        __syncthreads();

        // ---- init acc with bias contribution ----
        #pragma unroll
        for (int jj = 0; jj < 8; ++jj) {
            const float bias = Dg[KCH * DGS + j0 + jj];
            #pragma unroll
            for (int rr = 0; rr < 4; ++rr) acc[jj][rr] = bias;
        }

        // ---- phase 1: GEMM over finalized prefix n < v0 ----
        const int vmine = v0 + vlo;
        const float* mrow = Mbase + (size_t)(vmine * C + c0) * N1;
        #pragma unroll 1
        for (int n = 0; n < v0; n += 4) {
            float pr[4][4];
            #pragma unroll
            for (int i = 0; i < 4; ++i) {
                const float4 p4 = *(const float4*)(&Pt[(n + i) * PTS + r0]);
                pr[i][0] = p4.x; pr[i][1] = p4.y; pr[i][2] = p4.z; pr[i][3] = p4.w;
            }
            #pragma unroll
            for (int jj = 0; jj < 8; ++jj) {
                const float* mr = mrow + jj * N1 + n;
                const float m0 = mr[0], m1 = mr[1], m2 = mr[2], m3 = mr[3];
                #pragma unroll
                for (int rr = 0; rr < 4; ++rr) {
                    float a = acc[jj][rr];
                    a = fmaf(m0, pr[0][rr], a);
                    a = fmaf(m1, pr[1][rr], a);
                    a = fmaf(m2, pr[2][rr], a);
                    a = fmaf(m3, pr[3][rr], a);
                    acc[jj][rr] = a;
                }
            }
        }

        // ---- phase 2: 16 sequential clamp steps ----
        #pragma unroll 1
        for (int vl = 0; vl < KCH; ++vl) {
            if (vlo == vl) {
                // my accs are complete dots for v = v0+vl (prefix + bias + chunk cols < vl)
                float lw[4], up[4];
                #pragma unroll
                for (int rr = 0; rr < 4; ++rr) {
                    float a = acc[0][rr];
                    if (mat == 0) {
                        #pragma unroll
                        for (int jj = 1; jj < 8; ++jj) a = fmaxf(a, acc[jj][rr]);
                    } else {
                        #pragma unroll
                        for (int jj = 1; jj < 8; ++jj) a = fminf(a, acc[jj][rr]);
                    }
                    const float o = __shfl_xor(a, 8, 64);        // merge ch partner
                    a = (mat == 0) ? fmaxf(a, o) : fminf(a, o);
                    const float x = __shfl_xor(a, 16, 64);       // swap pos/neg
                    lw[rr] = (mat == 0) ? a : x;
                    up[rr] = (mat == 0) ? x : a;
                }
                if ((mat | ch) == 0) {   // 8 lanes cover all 32 rows
                    float* prow = &Pt[(v0 + vl) * PTS + r0];
                    const float4 po = *(const float4*)prow;
                    float4 pc;
                    pc.x = fminf(fmaxf(po.x, lw[0]), up[0]);
                    pc.y = fminf(fmaxf(po.y, lw[1]), up[1]);
                    pc.z = fminf(fmaxf(po.z, lw[2]), up[2]);
                    pc.w = fminf(fmaxf(po.w, lw[3]), up[3]);
                    *(float4*)prow = pc;
                }
            }
            __syncthreads();
            // rank-1 update with the just-finalized column; pre-masked zeros make
            // this exact for threads whose v' <= v0+vl (adds 0).
            const float4 pn4 = *(const float4*)(&Pt[(v0 + vl) * PTS + r0]);
            const float pn[4] = {pn4.x, pn4.y, pn4.z, pn4.w};
            const float4 d0 = *(const float4*)(&Dg[vl * DGS + j0]);
            const float4 d1 = *(const float4*)(&Dg[vl * DGS + j0 + 4]);
            const float dv[8] = {d0.x, d0.y, d0.z, d0.w, d1.x, d1.y, d1.z, d1.w};
            #pragma unroll
            for (int jj = 0; jj < 8; ++jj) {
                #pragma unroll
                for (int rr = 0; rr < 4; ++rr)
                    acc[jj][rr] = fmaf(dv[jj], pn[rr], acc[jj][rr]);
            }
        }
    }

    __syncthreads();

    // ---- epilogue: write corrected P (columns 0..511) ----
    {
        const int r = tid >> 4, seg = tid & 15;
        float* orow = out + (size_t)(b0 + r) * V + seg * 32;
        #pragma unroll
        for (int k = 0; k < 32; k += 4) {
            const int n = seg * 32 + k;
            float4 o;
            o.x = Pt[(n + 0) * PTS + r];
            o.y = Pt[(n + 1) * PTS + r];
            o.z = Pt[(n + 2) * PTS + r];
            o.w = Pt[(n + 3) * PTS + r];
            *(float4*)(orow + k) = o;
        }
    }
}

extern "C" void kernel_launch(void* const* d_in, const int* in_sizes, int n_in,
                              void* d_out, int out_size, void* d_ws, size_t ws_size,
                              hipStream_t stream) {
    const float* preds = (const float*)d_in[0];
    const float* pos   = (const float*)d_in[1];
    const float* neg   = (const float*)d_in[2];
    float* o = (float*)d_out;
    shield_kernel<<<dim3(BATCH / RB), dim3(NTHREADS), 0, stream>>>(preds, pos, neg, o);
}

// Round 2
// 1283.492 us; speedup vs baseline: 1.2447x; 1.2447x over previous
//
#include <hip/hip_runtime.h>

#define BATCH    8192
#define V        512
#define C        16
#define N1       513
#define KCH      16
#define NCHUNKS  32
#define RB       16     // batch rows per block
#define NT       256    // threads per block
#define PTS      16     // Pt row stride (floats)
#define JW       512    // j-width of repacked Mb rows: j = 32*vlo + 16*mat + 8*ch + jj
#define TS       513    // repack LDS tile stride

// ---------------- repack: M[v][c][n] -> Mb[cc][n][j],  j = 32*vlo+16*mat+8*ch+jj ----
// (c = j&15, mat = bit4, vlo = j>>5; v = 16*cc + vlo). Makes phase-1 M loads
// contiguous across the wave (lane jg reads j0..j0+7 -> 256B/wave segments).
__global__ __launch_bounds__(NT)
void repack_kernel(const float* __restrict__ pos, const float* __restrict__ neg,
                   float* __restrict__ Mb)
{
    __shared__ float T[16 * TS];
    const int t    = threadIdx.x;
    const int tile = blockIdx.x;         // 0..32 (n tiles of 16; last has 1)
    const int cc   = blockIdx.y;         // 0..31
    const int n0   = tile * 16;
    const int nmax = (n0 + 16 <= N1) ? 16 : (N1 - n0);

    #pragma unroll 4
    for (int e = t; e < JW * 16; e += NT) {          // read: coalesced-ish along n
        const int j = e >> 4, nf = e & 15;
        if (nf < nmax) {
            const int c = j & 15, mt = (j >> 4) & 1, vlo = j >> 5;
            const int v = cc * 16 + vlo;
            const float* src = mt ? neg : pos;
            T[nf * TS + j] = src[(size_t)(v * 16 + c) * N1 + n0 + nf];
        }
    }
    __syncthreads();
    #pragma unroll 4
    for (int e = t; e < JW * 16; e += NT) {          // write: fully coalesced over j
        const int j = e & (JW - 1), nf = e >> 9;
        if (nf < nmax)
            Mb[((size_t)cc * N1 + n0 + nf) * JW + j] = T[nf * TS + j];
    }
}

// ---------------- main kernel --------------------------------------------------
// tid = rg + 4*jg ; rg: 4-row group (r0=4*rg, 16 rows/block)
// jg = ch + 2*mat + 4*vlo ; j0 = 8*jg ; c0 = 8*ch
template<bool PACKED>
__global__ __launch_bounds__(NT, 2)
void shield_main(const float* __restrict__ preds,
                 const float* __restrict__ pos,
                 const float* __restrict__ neg,
                 const float* __restrict__ Mb,
                 float* __restrict__ out)
{
    __shared__ float Pt[N1 * PTS];      // 32.8 KB -> 2+ blocks/CU

    const int tid = threadIdx.x;
    const int b0  = blockIdx.x * RB;

    const int rg  = tid & 3;
    const int jg  = tid >> 2;
    const int ch  = jg & 1;
    const int mat = (jg >> 1) & 1;
    const int vlo = jg >> 2;
    const int r0  = rg * 4;
    const int c0  = ch * 8;
    const int j0  = jg * 8;

    // ---- load P tile transposed into LDS ----
    {
        const int r = tid >> 4, seg = tid & 15;
        const float* prow = preds + (size_t)(b0 + r) * V + seg * 32;
        #pragma unroll
        for (int k = 0; k < 32; k += 4) {
            const float4 p4 = *(const float4*)(prow + k);
            const int n = seg * 32 + k;
            Pt[(n + 0) * PTS + r] = p4.x;
            Pt[(n + 1) * PTS + r] = p4.y;
            Pt[(n + 2) * PTS + r] = p4.z;
            Pt[(n + 3) * PTS + r] = p4.w;
        }
        if (tid < RB) Pt[V * PTS + tid] = 1.0f;     // bias row
    }
    __syncthreads();

    const float* Msrc = mat ? neg : pos;
    float acc[8][4];

    #pragma unroll 1
    for (int chunk = 0; chunk < NCHUNKS; ++chunk) {
        const int v0 = chunk * KCH;
        const float* mchunk = PACKED ? (Mb + (size_t)chunk * N1 * JW) : nullptr;
        const float* mrow   = PACKED ? nullptr
                            : (Msrc + (size_t)((v0 + vlo) * C + c0) * N1);

        // ---- init acc with bias (column 512) ----
        float bias[8];
        if (PACKED) {
            const float4 b0v = *(const float4*)(mchunk + (size_t)V * JW + j0);
            const float4 b1v = *(const float4*)(mchunk + (size_t)V * JW + j0 + 4);
            bias[0]=b0v.x; bias[1]=b0v.y; bias[2]=b0v.z; bias[3]=b0v.w;
            bias[4]=b1v.x; bias[5]=b1v.y; bias[6]=b1v.z; bias[7]=b1v.w;
        } else {
            #pragma unroll
            for (int jj = 0; jj < 8; ++jj) bias[jj] = mrow[jj * N1 + V];
        }
        #pragma unroll
        for (int jj = 0; jj < 8; ++jj)
            #pragma unroll
            for (int rr = 0; rr < 4; ++rr) acc[jj][rr] = bias[jj];

        // ---- phase 1: GEMM over finalized prefix n < v0 ----
        #pragma unroll 1
        for (int n = 0; n < v0; n += 4) {
            float pr[4][4];
            float m[4][8];
            #pragma unroll
            for (int i = 0; i < 4; ++i) {
                const float4 p4 = *(const float4*)(&Pt[(n + i) * PTS + r0]);
                pr[i][0] = p4.x; pr[i][1] = p4.y; pr[i][2] = p4.z; pr[i][3] = p4.w;
            }
            if (PACKED) {
                #pragma unroll
                for (int i = 0; i < 4; ++i) {
                    const float4 a0 = *(const float4*)(mchunk + (size_t)(n + i) * JW + j0);
                    const float4 a1 = *(const float4*)(mchunk + (size_t)(n + i) * JW + j0 + 4);
                    m[i][0]=a0.x; m[i][1]=a0.y; m[i][2]=a0.z; m[i][3]=a0.w;
                    m[i][4]=a1.x; m[i][5]=a1.y; m[i][6]=a1.z; m[i][7]=a1.w;
                }
            } else {
                #pragma unroll
                for (int jj = 0; jj < 8; ++jj) {
                    const float* mr = mrow + jj * N1 + n;
                    m[0][jj]=mr[0]; m[1][jj]=mr[1]; m[2][jj]=mr[2]; m[3][jj]=mr[3];
                }
            }
            #pragma unroll
            for (int jj = 0; jj < 8; ++jj) {
                #pragma unroll
                for (int rr = 0; rr < 4; ++rr) {
                    float a = acc[jj][rr];
                    a = fmaf(m[0][jj], pr[0][rr], a);
                    a = fmaf(m[1][jj], pr[1][rr], a);
                    a = fmaf(m[2][jj], pr[2][rr], a);
                    a = fmaf(m[3][jj], pr[3][rr], a);
                    acc[jj][rr] = a;
                }
            }
        }

        // ---- phase 2: 16 sequential clamp steps ----
        #pragma unroll 1
        for (int vl = 0; vl < KCH; ++vl) {
            const int vcur = v0 + vl;
            // prefetch dv (independent of the barrier / Pt write)
            float dv[8];
            if (PACKED) {
                const float4 d0 = *(const float4*)(mchunk + (size_t)vcur * JW + j0);
                const float4 d1 = *(const float4*)(mchunk + (size_t)vcur * JW + j0 + 4);
                dv[0]=d0.x; dv[1]=d0.y; dv[2]=d0.z; dv[3]=d0.w;
                dv[4]=d1.x; dv[5]=d1.y; dv[6]=d1.z; dv[7]=d1.w;
            } else {
                #pragma unroll
                for (int jj = 0; jj < 8; ++jj) dv[jj] = mrow[jj * N1 + vcur];
            }

            if (vlo == vl) {
                float lw[4], up[4];
                #pragma unroll
                for (int rr = 0; rr < 4; ++rr) {
                    float a = acc[0][rr];
                    if (mat == 0) {
                        #pragma unroll
                        for (int jj = 1; jj < 8; ++jj) a = fmaxf(a, acc[jj][rr]);
                    } else {
                        #pragma unroll
                        for (int jj = 1; jj < 8; ++jj) a = fminf(a, acc[jj][rr]);
                    }
                    const float o = __shfl_xor(a, 4, 64);      // merge ch partner
                    a = (mat == 0) ? fmaxf(a, o) : fminf(a, o);
                    const float x = __shfl_xor(a, 8, 64);      // exchange pos/neg
                    lw[rr] = (mat == 0) ? a : x;
                    up[rr] = (mat == 0) ? x : a;
                }
                if ((mat | ch) == 0) {                         // 4 lanes cover 16 rows
                    float* prow = &Pt[vcur * PTS + r0];
                    const float4 po = *(const float4*)prow;
                    float4 pc;
                    pc.x = fminf(fmaxf(po.x, lw[0]), up[0]);
                    pc.y = fminf(fmaxf(po.y, lw[1]), up[1]);
                    pc.z = fminf(fmaxf(po.z, lw[2]), up[2]);
                    pc.w = fminf(fmaxf(po.w, lw[3]), up[3]);
                    *(float4*)prow = pc;
                }
            }
            __syncthreads();
            // rank-1 update; masked zeros make it a no-op for vl >= vlo (exact)
            const float4 pn4 = *(const float4*)(&Pt[vcur * PTS + r0]);
            const float pn[4] = {pn4.x, pn4.y, pn4.z, pn4.w};
            #pragma unroll
            for (int jj = 0; jj < 8; ++jj)
                #pragma unroll
                for (int rr = 0; rr < 4; ++rr)
                    acc[jj][rr] = fmaf(dv[jj], pn[rr], acc[jj][rr]);
        }
    }

    __syncthreads();

    // ---- epilogue ----
    {
        const int r = tid >> 4, seg = tid & 15;
        float* orow = out + (size_t)(b0 + r) * V + seg * 32;
        #pragma unroll
        for (int k = 0; k < 32; k += 4) {
            const int n = seg * 32 + k;
            float4 o;
            o.x = Pt[(n + 0) * PTS + r];
            o.y = Pt[(n + 1) * PTS + r];
            o.z = Pt[(n + 2) * PTS + r];
            o.w = Pt[(n + 3) * PTS + r];
            *(float4*)(orow + k) = o;
        }
    }
}

extern "C" void kernel_launch(void* const* d_in, const int* in_sizes, int n_in,
                              void* d_out, int out_size, void* d_ws, size_t ws_size,
                              hipStream_t stream) {
    const float* preds = (const float*)d_in[0];
    const float* pos   = (const float*)d_in[1];
    const float* neg   = (const float*)d_in[2];
    float* o = (float*)d_out;
    const size_t need = (size_t)NCHUNKS * N1 * JW * sizeof(float);  // 33.6 MB
    if (ws_size >= need) {
        float* Mb = (float*)d_ws;
        repack_kernel<<<dim3(33, 32), dim3(NT), 0, stream>>>(pos, neg, Mb);
        shield_main<true><<<dim3(BATCH / RB), dim3(NT), 0, stream>>>(preds, pos, neg, Mb, o);
    } else {
        shield_main<false><<<dim3(BATCH / RB), dim3(NT), 0, stream>>>(preds, pos, neg, nullptr, o);
    }
}

// Round 3
// 1280.027 us; speedup vs baseline: 1.2480x; 1.0027x over previous
//
#include <hip/hip_runtime.h>

#define BATCH    8192
#define V        512
#define C        16
#define N1       513
#define KCH      16
#define NCHUNKS  32
#define RB       16     // batch rows per block
#define NT       256    // threads per block (4 waves)
#define PTS      16     // Pt layout [n][16 rows]
#define JW       512    // packed j-width: j = 32*vlo + 16*mat + 8*ch + jj
#define SJ       524    // S row stride (floats), padded
#define TS       513    // repack LDS tile stride

// ---------------- repack: M[v][c][n] -> Mb[cc][n][j] --------------------------
__global__ __launch_bounds__(NT)
void repack_kernel(const float* __restrict__ pos, const float* __restrict__ neg,
                   float* __restrict__ Mb)
{
    __shared__ float T[16 * TS];
    const int t    = threadIdx.x;
    const int tile = blockIdx.x;         // n tiles of 16 (last partial)
    const int cc   = blockIdx.y;
    const int n0   = tile * 16;
    const int nmax = (n0 + 16 <= N1) ? 16 : (N1 - n0);

    #pragma unroll 4
    for (int e = t; e < JW * 16; e += NT) {
        const int j = e >> 4, nf = e & 15;
        if (nf < nmax) {
            const int c = j & 15, mt = (j >> 4) & 1, vlo = j >> 5;
            const int v = cc * 16 + vlo;
            const float* src = mt ? neg : pos;
            T[nf * TS + j] = src[(size_t)(v * 16 + c) * N1 + n0 + nf];
        }
    }
    __syncthreads();
    #pragma unroll 4
    for (int e = t; e < JW * 16; e += NT) {
        const int j = e & (JW - 1), nf = e >> 9;
        if (nf < nmax)
            Mb[((size_t)cc * N1 + n0 + nf) * JW + j] = T[nf * TS + j];
    }
}

// ---------------- main kernel --------------------------------------------------
// Phase 1: tid = rg + 4*jg; thread tile = 8 j x 4 rows (acc[8][4]).
// Phase 2: wave-autonomous. Wave wv owns rows 4wv..4wv+3; lane l owns
//          j = 8l..8l+7 (s2[8][4]); all 16 serial steps use shuffles only.
template<bool PACKED>
__global__ __launch_bounds__(NT, 2)
void shield_main(const float* __restrict__ preds,
                 const float* __restrict__ pos,
                 const float* __restrict__ neg,
                 const float* __restrict__ Mb,
                 float* __restrict__ out)
{
    __shared__ float Pt[V * PTS];   // [n][r] fp32, 32.8 KB
    __shared__ float S[RB * SJ];    // acc hand-off [r][j], 33.5 KB

    const int tid = threadIdx.x;
    const int b0  = blockIdx.x * RB;

    // phase-1 mapping
    const int rg = tid & 3, jg = tid >> 2;
    const int r0 = rg * 4, j0 = jg * 8;
    const int vlo1 = jg >> 2, ch1 = jg & 1, mat1 = (jg >> 1) & 1;

    // phase-2 mapping
    const int lane = tid & 63;
    const int wv   = tid >> 6;
    const int rp0  = wv * 4;                 // this wave's first row
    const int vloL = lane >> 2;
    const int matL = (lane >> 1) & 1;
    const int chL  = lane & 1;
    const float sgn = matL ? -1.0f : 1.0f;   // negation trick: all reduces are max

    // ---- load P tile into LDS [n][r] ----
    {
        const int r = tid >> 4, seg = tid & 15;
        const float* prow = preds + (size_t)(b0 + r) * V + seg * 32;
        #pragma unroll
        for (int k = 0; k < 32; k += 4) {
            const float4 p4 = *(const float4*)(prow + k);
            const int n = seg * 32 + k;
            Pt[(n + 0) * PTS + r] = p4.x;
            Pt[(n + 1) * PTS + r] = p4.y;
            Pt[(n + 2) * PTS + r] = p4.z;
            Pt[(n + 3) * PTS + r] = p4.w;
        }
    }

    const float* Msrc1 = mat1 ? neg : pos;                       // phase-1 fallback
    const float* MsrcL = matL ? neg : pos;                       // phase-2 fallback
    float acc[8][4];

    #pragma unroll 1
    for (int chunk = 0; chunk < NCHUNKS; ++chunk) {
        const int v0 = chunk * KCH;
        __syncthreads();   // prev phase-2 Pt writes visible; S reusable

        const float* mchunk = PACKED ? (Mb + (size_t)chunk * N1 * JW) : nullptr;
        const float* mrow   = PACKED ? nullptr
                            : (Msrc1 + (size_t)((v0 + vlo1) * C + ch1 * 8) * N1);

        // ---- init acc with bias (column 512) ----
        float bias[8];
        if (PACKED) {
            const float4 bv0 = *(const float4*)(mchunk + (size_t)V * JW + j0);
            const float4 bv1 = *(const float4*)(mchunk + (size_t)V * JW + j0 + 4);
            bias[0]=bv0.x; bias[1]=bv0.y; bias[2]=bv0.z; bias[3]=bv0.w;
            bias[4]=bv1.x; bias[5]=bv1.y; bias[6]=bv1.z; bias[7]=bv1.w;
        } else {
            #pragma unroll
            for (int jj = 0; jj < 8; ++jj) bias[jj] = mrow[jj * N1 + V];
        }
        #pragma unroll
        for (int jj = 0; jj < 8; ++jj)
            #pragma unroll
            for (int rr = 0; rr < 4; ++rr) acc[jj][rr] = bias[jj];

        // ---- phase 1: GEMM over finalized prefix n < v0 ----
        #pragma unroll 1
        for (int n = 0; n < v0; n += 4) {
            float pr[4][4];
            float m[4][8];
            #pragma unroll
            for (int i = 0; i < 4; ++i) {
                const float4 p4 = *(const float4*)(&Pt[(n + i) * PTS + r0]);
                pr[i][0] = p4.x; pr[i][1] = p4.y; pr[i][2] = p4.z; pr[i][3] = p4.w;
            }
            if (PACKED) {
                #pragma unroll
                for (int i = 0; i < 4; ++i) {
                    const float4 a0 = *(const float4*)(mchunk + (size_t)(n + i) * JW + j0);
                    const float4 a1 = *(const float4*)(mchunk + (size_t)(n + i) * JW + j0 + 4);
                    m[i][0]=a0.x; m[i][1]=a0.y; m[i][2]=a0.z; m[i][3]=a0.w;
                    m[i][4]=a1.x; m[i][5]=a1.y; m[i][6]=a1.z; m[i][7]=a1.w;
                }
            } else {
                #pragma unroll
                for (int jj = 0; jj < 8; ++jj) {
                    const float* mr = mrow + jj * N1 + n;
                    m[0][jj]=mr[0]; m[1][jj]=mr[1]; m[2][jj]=mr[2]; m[3][jj]=mr[3];
                }
            }
            #pragma unroll
            for (int jj = 0; jj < 8; ++jj) {
                #pragma unroll
                for (int rr = 0; rr < 4; ++rr) {
                    float a = acc[jj][rr];
                    a = fmaf(m[0][jj], pr[0][rr], a);
                    a = fmaf(m[1][jj], pr[1][rr], a);
                    a = fmaf(m[2][jj], pr[2][rr], a);
                    a = fmaf(m[3][jj], pr[3][rr], a);
                    acc[jj][rr] = a;
                }
            }
        }

        // ---- dump acc -> S[r][j] ----
        #pragma unroll
        for (int rr = 0; rr < 4; ++rr) {
            float4 a0, a1;
            a0.x=acc[0][rr]; a0.y=acc[1][rr]; a0.z=acc[2][rr]; a0.w=acc[3][rr];
            a1.x=acc[4][rr]; a1.y=acc[5][rr]; a1.z=acc[6][rr]; a1.w=acc[7][rr];
            *(float4*)(&S[(r0 + rr) * SJ + j0])     = a0;
            *(float4*)(&S[(r0 + rr) * SJ + j0 + 4]) = a1;
        }
        __syncthreads();

        // ---- phase 2: wave-local, barrier-free 16-step chain ----
        float s2[8][4];
        #pragma unroll
        for (int r = 0; r < 4; ++r) {
            const float4 a0 = *(const float4*)(&S[(rp0 + r) * SJ + 8 * lane]);
            const float4 a1 = *(const float4*)(&S[(rp0 + r) * SJ + 8 * lane + 4]);
            s2[0][r]=sgn*a0.x; s2[1][r]=sgn*a0.y; s2[2][r]=sgn*a0.z; s2[3][r]=sgn*a0.w;
            s2[4][r]=sgn*a1.x; s2[5][r]=sgn*a1.y; s2[6][r]=sgn*a1.z; s2[7][r]=sgn*a1.w;
        }

        // prefetch dv, pold for vl=0
        float dv[8];
        if (PACKED) {
            const float4 d0 = *(const float4*)(mchunk + (size_t)v0 * JW + 8 * lane);
            const float4 d1 = *(const float4*)(mchunk + (size_t)v0 * JW + 8 * lane + 4);
            dv[0]=d0.x; dv[1]=d0.y; dv[2]=d0.z; dv[3]=d0.w;
            dv[4]=d1.x; dv[5]=d1.y; dv[6]=d1.z; dv[7]=d1.w;
        } else {
            const float* drow = MsrcL + (size_t)((v0 + vloL) * C + chL * 8) * N1;
            #pragma unroll
            for (int jj = 0; jj < 8; ++jj) dv[jj] = drow[jj * N1 + v0];
        }
        float4 poldv = *(const float4*)(&Pt[v0 * PTS + rp0]);

        #pragma unroll 1
        for (int vl = 0; vl < KCH; ++vl) {
            const int vcur = v0 + vl;
            float dvc[8];
            #pragma unroll
            for (int jj = 0; jj < 8; ++jj) dvc[jj] = dv[jj];
            const float po[4] = {poldv.x, poldv.y, poldv.z, poldv.w};

            // prefetch next step (off the dependency chain)
            if (vl + 1 < KCH) {
                if (PACKED) {
                    const float4 d0 = *(const float4*)(mchunk + (size_t)(vcur + 1) * JW + 8 * lane);
                    const float4 d1 = *(const float4*)(mchunk + (size_t)(vcur + 1) * JW + 8 * lane + 4);
                    dv[0]=d0.x; dv[1]=d0.y; dv[2]=d0.z; dv[3]=d0.w;
                    dv[4]=d1.x; dv[5]=d1.y; dv[6]=d1.z; dv[7]=d1.w;
                } else {
                    const float* drow = MsrcL + (size_t)((v0 + vloL) * C + chL * 8) * N1;
                    #pragma unroll
                    for (int jj = 0; jj < 8; ++jj) dv[jj] = drow[jj * N1 + vcur + 1];
                }
                poldv = *(const float4*)(&Pt[(vcur + 1) * PTS + rp0]);
            }

            // in-lane reduce (all values in negated space for mat=1 -> max everywhere)
            float red[4], oth[4];
            #pragma unroll
            for (int r = 0; r < 4; ++r) {
                float a = fmaxf(fmaxf(s2[0][r], s2[1][r]), fmaxf(s2[2][r], s2[3][r]));
                float b = fmaxf(fmaxf(s2[4][r], s2[5][r]), fmaxf(s2[6][r], s2[7][r]));
                red[r] = fmaxf(a, b);
            }
            #pragma unroll
            for (int r = 0; r < 4; ++r)
                red[r] = fmaxf(red[r], __shfl_xor(red[r], 1, 64));   // merge ch
            #pragma unroll
            for (int r = 0; r < 4; ++r)
                oth[r] = __shfl_xor(red[r], 2, 64);                  // other mat's value

            // broadcast owner's (lane 4*vl: mat=0,ch=0) lower / -upper
            float pc[4];
            #pragma unroll
            for (int r = 0; r < 4; ++r) {
                const float lw  = __shfl(red[r], 4 * vl, 64);
                const float nup = __shfl(oth[r], 4 * vl, 64);
                pc[r] = fminf(fmaxf(po[r], lw), -nup);
            }
            if (lane == 4 * vl) {
                float4 pcv; pcv.x=pc[0]; pcv.y=pc[1]; pcv.z=pc[2]; pcv.w=pc[3];
                *(float4*)(&Pt[vcur * PTS + rp0]) = pcv;             // own rows only
            }

            // rank-1 update (masked zeros keep finished slots exact)
            #pragma unroll
            for (int jj = 0; jj < 8; ++jj) {
                const float sdv = sgn * dvc[jj];
                #pragma unroll
                for (int r = 0; r < 4; ++r)
                    s2[jj][r] = fmaf(sdv, pc[r], s2[jj][r]);
            }
        }
    }

    __syncthreads();

    // ---- epilogue ----
    {
        const int r = tid >> 4, seg = tid & 15;
        float* orow = out + (size_t)(b0 + r) * V + seg * 32;
        #pragma unroll
        for (int k = 0; k < 32; k += 4) {
            const int n = seg * 32 + k;
            float4 o;
            o.x = Pt[(n + 0) * PTS + r];
            o.y = Pt[(n + 1) * PTS + r];
            o.z = Pt[(n + 2) * PTS + r];
            o.w = Pt[(n + 3) * PTS + r];
            *(float4*)(orow + k) = o;
        }
    }
}

extern "C" void kernel_launch(void* const* d_in, const int* in_sizes, int n_in,
                              void* d_out, int out_size, void* d_ws, size_t ws_size,
                              hipStream_t stream) {
    const float* preds = (const float*)d_in[0];
    const float* pos   = (const float*)d_in[1];
    const float* neg   = (const float*)d_in[2];
    float* o = (float*)d_out;
    const size_t need = (size_t)NCHUNKS * N1 * JW * sizeof(float);  // 33.6 MB
    if (ws_size >= need) {
        float* Mb = (float*)d_ws;
        repack_kernel<<<dim3(33, 32), dim3(NT), 0, stream>>>(pos, neg, Mb);
        shield_main<true><<<dim3(BATCH / RB), dim3(NT), 0, stream>>>(preds, pos, neg, Mb, o);
    } else {
        shield_main<false><<<dim3(BATCH / RB), dim3(NT), 0, stream>>>(preds, pos, neg, nullptr, o);
    }
}

// Round 6
// 713.029 us; speedup vs baseline: 2.2405x; 1.7952x over previous
//
#include <hip/hip_runtime.h>

#define BATCH 8192
#define V 512
#define C 16
#define N1 513
#define KCH 16
#define NCHUNKS 32
#define RB 32            // batch rows per block -> grid 256 = 1 block/CU
#define NT 512           // 8 waves
#define PKS 520          // Phi/Plo row stride, bf16 elems (1040 B, 16B-aligned)
#define SJ 520           // S row stride, floats

typedef __bf16 bf16_t;
typedef bf16_t bf16x8 __attribute__((ext_vector_type(8)));
typedef float f32x4 __attribute__((ext_vector_type(4)));

// ---- workspace layout (bytes) --------------------------------------------------
// Mhi/Mlo: fragment-linear packed bf16, EPP elems each.
//   chunk cc (1..31): nkb = ceil(cc/2) k-blocks of 32 (zero-padded past 16*cc);
//   chunk base elems = 16384 * floor(cc^2/4); block kb, tile t (= 2*vl+mat, 0..31):
//   elem idx = chb + (kb*32 + t)*512 + (c + 16*q)*8 + jj  <->  M[v=16cc+vl][c][k=kb*32+8q+jj]
// Dv: fp32 [cc][vl][512 j] exact diagonal blocks; Bv: fp32 [cc][512 j] exact bias.
#define EPP      4194304ull
#define MLO_OFF  (EPP * 2ull)
#define DV_OFF   (EPP * 4ull)
#define BV_OFF   (DV_OFF + 1048576ull)

__device__ __forceinline__ f32x4 mfma16(bf16x8 a, bf16x8 b, f32x4 c) {
    return __builtin_amdgcn_mfma_f32_16x16x32_bf16(a, b, c, 0, 0, 0);
}

// ---- repack M -> fragment-linear bf16 hi/lo ------------------------------------
__global__ __launch_bounds__(256)
void repack_m(const float* __restrict__ pos, const float* __restrict__ neg,
              bf16_t* __restrict__ Mhi, bf16_t* __restrict__ Mlo)
{
    const int cc  = blockIdx.x + 1;          // 1..31
    const int kb  = blockIdx.y;              // 0..15
    const int nkb = (cc + 1) >> 1;
    if (kb >= nkb) return;
    const int klen = 16 * cc;
    const size_t base = 16384ull * (size_t)((cc * cc) / 4) + (size_t)kb * 16384ull;
    for (int e = threadIdx.x; e < 16384; e += 256) {
        const int t = e >> 9, s = (e >> 3) & 63, jj = e & 7;
        const int c = s & 15, q = s >> 4;
        const int v = cc * 16 + (t >> 1);
        const int k = kb * 32 + 8 * q + jj;
        const float* src = (t & 1) ? neg : pos;
        const float x = (k < klen) ? src[(size_t)(v * 16 + c) * N1 + k] : 0.0f;
        const bf16_t h = (bf16_t)x;
        Mhi[base + e] = h;
        Mlo[base + e] = (bf16_t)(x - (float)h);
    }
}

// ---- gather exact fp32 diagonal blocks (Dv) and bias (Bv) ----------------------
// j = 32*vlo + 16*mat + c
__global__ __launch_bounds__(256)
void repack_dv(const float* __restrict__ pos, const float* __restrict__ neg,
               float* __restrict__ Dv, float* __restrict__ Bv)
{
    const int e = blockIdx.x * 256 + threadIdx.x;
    if (e < 262144) {
        const int cc = e >> 13, vl = (e >> 9) & 15, j = e & 511;
        const int v = cc * 16 + (j >> 5), c = j & 15;
        const float* src = (j & 16) ? neg : pos;
        Dv[e] = src[(size_t)(v * 16 + c) * N1 + cc * 16 + vl];
    } else {
        const int e2 = e - 262144;
        const int cc = e2 >> 9, j = e2 & 511;
        const int v = cc * 16 + (j >> 5), c = j & 15;
        const float* src = (j & 16) ? neg : pos;
        Bv[e2] = src[(size_t)(v * 16 + c) * N1 + V];
    }
}

// ---- main kernel ---------------------------------------------------------------
// Phase 1: D[32 r][512 j] = P[r][k<v0] * M[j][k] via 16x16x32 bf16 MFMA, split
//   hi/lo (3 passes: AhBh + AlBh + AhBl). Wave w owns j-tiles t = 4w..4w+3.
//   A-frag: P[m=lane&15 (+16 for half 1)][k0 + 8*(lane>>4) + jj]  (LDS b128)
//   B-frag: fragment-linear global dwordx4 (1KB/wave, fully coalesced)
//   C-frag: row = (lane>>4)*4 + reg, col = lane&15                (m89-verified)
// Phase 2: barrier-free in-wave serial chain (R3 structure), exact fp32 Dv/Bv.
__global__ __launch_bounds__(NT, 2)
void shield_mfma(const float* __restrict__ preds,
                 const bf16_t* __restrict__ Mhi, const bf16_t* __restrict__ Mlo,
                 const float* __restrict__ Dv, const float* __restrict__ Bv,
                 float* __restrict__ out)
{
    __shared__ bf16_t Phi[RB * PKS];   // 33,280 B
    __shared__ bf16_t Plo[RB * PKS];   // 33,280 B
    __shared__ float  S[RB * SJ];      // 66,560 B  (total 133,120 -> 1 block/CU)

    const int tid  = threadIdx.x;
    const int b0   = blockIdx.x * RB;
    const int lane = tid & 63;
    const int w    = tid >> 6;
    const int cq   = lane & 15;
    const int q    = lane >> 4;

    // phase-2 mapping: lane owns j = 8*lane..8*lane+7; lane = 4*vlo + 2*mat + ch
    const int   rp0  = w * 4;
    const int   matL = (lane >> 1) & 1;
    const float sgn  = matL ? -1.0f : 1.0f;   // negation trick: all reduces are max

    // ---- load preds -> Phi/Plo ----
    {
        const int r = tid >> 4, seg = tid & 15;
        const float* prow = preds + (size_t)(b0 + r) * V + seg * 32;
        #pragma unroll
        for (int k = 0; k < 32; k += 4) {
            const float4 p4 = *(const float4*)(prow + k);
            const int n = seg * 32 + k;
            const float xs[4] = {p4.x, p4.y, p4.z, p4.w};
            #pragma unroll
            for (int i = 0; i < 4; ++i) {
                const bf16_t h = (bf16_t)xs[i];
                Phi[r * PKS + n + i] = h;
                Plo[r * PKS + n + i] = (bf16_t)(xs[i] - (float)h);
            }
        }
    }

    int tJ[4];
    #pragma unroll
    for (int tt = 0; tt < 4; ++tt) tJ[tt] = ((4 * w + tt) << 4) + cq;
    const int aoff0 = cq * PKS + 8 * q;
    const int aoff1 = (16 + cq) * PKS + 8 * q;

    #pragma unroll 1
    for (int cc = 0; cc < NCHUNKS; ++cc) {
        const int v0 = cc * 16;
        __syncthreads();   // prev phase-2 Phi/Plo writes visible; S reusable

        // ---- init acc with exact fp32 bias ----
        f32x4 acc[2][4];
        #pragma unroll
        for (int tt = 0; tt < 4; ++tt) {
            const float b = Bv[(cc << 9) + tJ[tt]];
            const f32x4 bv = {b, b, b, b};
            acc[0][tt] = bv;
            acc[1][tt] = bv;
        }

        // ---- phase 1: split-bf16 MFMA GEMM over prefix ----
        if (cc > 0) {
            const int nkb = (cc + 1) >> 1;
            const size_t chb = 16384ull * (size_t)((cc * cc) / 4) + (size_t)lane * 8;
            const bf16_t* ph = Mhi + chb;
            const bf16_t* pl = Mlo + chb;
            bf16x8 bh[4], bl[4];
            #pragma unroll
            for (int tt = 0; tt < 4; ++tt) {
                const size_t o = (size_t)(4 * w + tt) * 512;
                bh[tt] = *(const bf16x8*)(ph + o);
                bl[tt] = *(const bf16x8*)(pl + o);
            }
            #pragma unroll 1
            for (int kb = 0; kb < nkb; ++kb) {
                const int k0 = kb * 32;
                const bf16x8 ah0 = *(const bf16x8*)(Phi + aoff0 + k0);
                const bf16x8 al0 = *(const bf16x8*)(Plo + aoff0 + k0);
                const bf16x8 ah1 = *(const bf16x8*)(Phi + aoff1 + k0);
                const bf16x8 al1 = *(const bf16x8*)(Plo + aoff1 + k0);
                bf16x8 nh[4], nl[4];
                const bool more = (kb + 1) < nkb;
                if (more) {
                    #pragma unroll
                    for (int tt = 0; tt < 4; ++tt) {
                        const size_t o = ((size_t)(kb + 1) * 32 + 4 * w + tt) * 512;
                        nh[tt] = *(const bf16x8*)(ph + o);
                        nl[tt] = *(const bf16x8*)(pl + o);
                    }
                }
                #pragma unroll
                for (int tt = 0; tt < 4; ++tt) {
                    acc[0][tt] = mfma16(ah0, bh[tt], acc[0][tt]);
                    acc[1][tt] = mfma16(ah1, bh[tt], acc[1][tt]);
                    acc[0][tt] = mfma16(al0, bh[tt], acc[0][tt]);
                    acc[1][tt] = mfma16(al1, bh[tt], acc[1][tt]);
                    acc[0][tt] = mfma16(ah0, bl[tt], acc[0][tt]);
                    acc[1][tt] = mfma16(ah1, bl[tt], acc[1][tt]);
                }
                if (more) {
                    #pragma unroll
                    for (int tt = 0; tt < 4; ++tt) { bh[tt] = nh[tt]; bl[tt] = nl[tt]; }
                }
            }
        }

        // ---- dump C-frags -> S[r][j] ----
        #pragma unroll
        for (int tt = 0; tt < 4; ++tt)
            #pragma unroll
            for (int reg = 0; reg < 4; ++reg) {
                S[(4 * q + reg) * SJ + tJ[tt]]      = acc[0][tt][reg];
                S[(16 + 4 * q + reg) * SJ + tJ[tt]] = acc[1][tt][reg];
            }
        __syncthreads();

        // ---- phase 2: barrier-free in-wave 16-step chain (rows rp0..rp0+3) ----
        float s2[8][4];
        #pragma unroll
        for (int r = 0; r < 4; ++r) {
            const float4 x0 = *(const float4*)(&S[(rp0 + r) * SJ + 8 * lane]);
            const float4 x1 = *(const float4*)(&S[(rp0 + r) * SJ + 8 * lane + 4]);
            s2[0][r] = sgn * x0.x; s2[1][r] = sgn * x0.y;
            s2[2][r] = sgn * x0.z; s2[3][r] = sgn * x0.w;
            s2[4][r] = sgn * x1.x; s2[5][r] = sgn * x1.y;
            s2[6][r] = sgn * x1.z; s2[7][r] = sgn * x1.w;
        }

        float dv[8], po[4];
        {
            const float* dp = Dv + ((size_t)(cc * 16) << 9) + 8 * lane;
            const float4 d0 = *(const float4*)(dp);
            const float4 d1 = *(const float4*)(dp + 4);
            dv[0]=d0.x; dv[1]=d0.y; dv[2]=d0.z; dv[3]=d0.w;
            dv[4]=d1.x; dv[5]=d1.y; dv[6]=d1.z; dv[7]=d1.w;
            #pragma unroll
            for (int r = 0; r < 4; ++r)
                po[r] = (float)Phi[(rp0 + r) * PKS + v0]
                      + (float)Plo[(rp0 + r) * PKS + v0];
        }

        #pragma unroll 1
        for (int vl = 0; vl < KCH; ++vl) {
            const int vcur = v0 + vl;
            float dvc[8], poc[4];
            #pragma unroll
            for (int jj = 0; jj < 8; ++jj) dvc[jj] = dv[jj];
            #pragma unroll
            for (int r = 0; r < 4; ++r) poc[r] = po[r];

            if (vl + 1 < KCH) {   // prefetch next step, off the chain
                const float* dp = Dv + ((size_t)(cc * 16 + vl + 1) << 9) + 8 * lane;
                const float4 d0 = *(const float4*)(dp);
                const float4 d1 = *(const float4*)(dp + 4);
                dv[0]=d0.x; dv[1]=d0.y; dv[2]=d0.z; dv[3]=d0.w;
                dv[4]=d1.x; dv[5]=d1.y; dv[6]=d1.z; dv[7]=d1.w;
                #pragma unroll
                for (int r = 0; r < 4; ++r)
                    po[r] = (float)Phi[(rp0 + r) * PKS + vcur + 1]
                          + (float)Plo[(rp0 + r) * PKS + vcur + 1];
            }

            // in-lane reduce (negated space -> max everywhere)
            float red[4], oth[4];
            #pragma unroll
            for (int r = 0; r < 4; ++r) {
                const float x = fmaxf(fmaxf(s2[0][r], s2[1][r]), fmaxf(s2[2][r], s2[3][r]));
                const float y = fmaxf(fmaxf(s2[4][r], s2[5][r]), fmaxf(s2[6][r], s2[7][r]));
                red[r] = fmaxf(x, y);
            }
            #pragma unroll
            for (int r = 0; r < 4; ++r)
                red[r] = fmaxf(red[r], __shfl_xor(red[r], 1, 64));   // merge ch
            #pragma unroll
            for (int r = 0; r < 4; ++r)
                oth[r] = __shfl_xor(red[r], 2, 64);                  // other mat

            float pc[4];
            #pragma unroll
            for (int r = 0; r < 4; ++r) {
                const float lw  = __shfl(red[r], 4 * vl, 64);
                const float nup = __shfl(oth[r], 4 * vl, 64);
                pc[r] = fminf(fmaxf(poc[r], lw), -nup);
            }
            if (lane == 4 * vl) {   // owner writes corrected value, hi/lo split
                #pragma unroll
                for (int r = 0; r < 4; ++r) {
                    const bf16_t h = (bf16_t)pc[r];
                    Phi[(rp0 + r) * PKS + vcur] = h;
                    Plo[(rp0 + r) * PKS + vcur] = (bf16_t)(pc[r] - (float)h);
                }
            }
            // exact fp32 rank-1 update (masked zeros -> no-op for finished slots)
            #pragma unroll
            for (int jj = 0; jj < 8; ++jj) {
                const float sdv = sgn * dvc[jj];
                #pragma unroll
                for (int r = 0; r < 4; ++r)
                    s2[jj][r] = fmaf(sdv, pc[r], s2[jj][r]);
            }
        }
    }

    __syncthreads();

    // ---- epilogue: out = hi + lo ----
    {
        const int r = tid >> 4, seg = tid & 15;
        float* orow = out + (size_t)(b0 + r) * V + seg * 32;
        #pragma unroll
        for (int k = 0; k < 32; k += 4) {
            const int n = seg * 32 + k;
            float4 o;
            o.x = (float)Phi[r * PKS + n + 0] + (float)Plo[r * PKS + n + 0];
            o.y = (float)Phi[r * PKS + n + 1] + (float)Plo[r * PKS + n + 1];
            o.z = (float)Phi[r * PKS + n + 2] + (float)Plo[r * PKS + n + 2];
            o.w = (float)Phi[r * PKS + n + 3] + (float)Plo[r * PKS + n + 3];
            *(float4*)(orow + k) = o;
        }
    }
}

extern "C" void kernel_launch(void* const* d_in, const int* in_sizes, int n_in,
                              void* d_out, int out_size, void* d_ws, size_t ws_size,
                              hipStream_t stream) {
    const float* preds = (const float*)d_in[0];
    const float* pos   = (const float*)d_in[1];
    const float* neg   = (const float*)d_in[2];
    float* o = (float*)d_out;
    char* base = (char*)d_ws;
    bf16_t* Mhi = (bf16_t*)base;
    bf16_t* Mlo = (bf16_t*)(base + MLO_OFF);
    float*  Dv  = (float*)(base + DV_OFF);
    float*  Bv  = (float*)(base + BV_OFF);
    // total ws need ~17.9 MB; R2/R3 confirmed ws_size >= 33.6 MB on this harness
    repack_m<<<dim3(31, 16), 256, 0, stream>>>(pos, neg, Mhi, Mlo);
    repack_dv<<<dim3(1088), 256, 0, stream>>>(pos, neg, Dv, Bv);
    shield_mfma<<<dim3(BATCH / RB), NT, 0, stream>>>(preds, Mhi, Mlo, Dv, Bv, o);
}

// Round 7
// 486.955 us; speedup vs baseline: 3.2806x; 1.4643x over previous
//
#include <hip/hip_runtime.h>

#define BATCH 8192
#define V 512
#define N1 513
#define KCH 16
#define NCHUNKS 32
#define RB 32            // rows per block -> grid 256
#define NT 512           // 8 waves
#define PKS 520          // Phi row stride (bf16 elems)
#define SJ 516           // S row stride (floats)

typedef __bf16 bf16_t;
typedef bf16_t bf16x8 __attribute__((ext_vector_type(8)));
typedef float f32x4 __attribute__((ext_vector_type(4)));

// workspace: Mhi (EPP bf16 elems, fragment-linear triangular pack), Dv, Bv
//   chunk cc in 1..31: nkb = ceil(cc/2) k-blocks of 32 (zero-pad past 16*cc);
//   base elems = 16384*floor(cc^2/4); elem = base + (kb*32 + t)*512 + lane*8 + jj
//   with t = 2*vl + mat (tile of 16 j), lane = c + 16*q, k = kb*32 + 8*q + jj.
// Dv: fp32 [cc][vl][512 j] exact diagonal coeffs; Bv: fp32 [cc][512 j] exact bias.
#define EPP 4194304ull
#define DV_OFF (EPP * 2ull)
#define BV_OFF (DV_OFF + 1048576ull)

__device__ __forceinline__ f32x4 mfma16(bf16x8 a, bf16x8 b, f32x4 c) {
    return __builtin_amdgcn_mfma_f32_16x16x32_bf16(a, b, c, 0, 0, 0);
}

__global__ __launch_bounds__(256)
void repack_m(const float* __restrict__ pos, const float* __restrict__ neg,
              bf16_t* __restrict__ Mhi)
{
    const int cc  = blockIdx.x + 1;          // 1..31
    const int kb  = blockIdx.y;
    const int nkb = (cc + 1) >> 1;
    if (kb >= nkb) return;
    const int klen = 16 * cc;
    const size_t base = 16384ull * (size_t)((cc * cc) / 4) + (size_t)kb * 16384ull;
    for (int e = threadIdx.x; e < 16384; e += 256) {
        const int t = e >> 9, s = (e >> 3) & 63, jj = e & 7;
        const int c = s & 15, q = s >> 4;
        const int v = cc * 16 + (t >> 1);
        const int k = kb * 32 + 8 * q + jj;
        const float* src = (t & 1) ? neg : pos;
        const float x = (k < klen) ? src[(size_t)(v * 16 + c) * N1 + k] : 0.0f;
        Mhi[base + e] = (bf16_t)x;
    }
}

// j = 32*vlo + 16*mat + c
__global__ __launch_bounds__(256)
void repack_dv(const float* __restrict__ pos, const float* __restrict__ neg,
               float* __restrict__ Dv, float* __restrict__ Bv)
{
    const int e = blockIdx.x * 256 + threadIdx.x;
    if (e < 262144) {
        const int cc = e >> 13, vl = (e >> 9) & 15, j = e & 511;
        const int v = cc * 16 + (j >> 5), c = j & 15;
        const float* src = (j & 16) ? neg : pos;
        Dv[e] = src[(size_t)(v * 16 + c) * N1 + cc * 16 + vl];
    } else {
        const int e2 = e - 262144;
        const int cc = e2 >> 9, j = e2 & 511;
        const int v = cc * 16 + (j >> 5), c = j & 15;
        const float* src = (j & 16) ? neg : pos;
        Bv[e2] = src[(size_t)(v * 16 + c) * N1 + V];
    }
}

// Fused kernel: per chunk cc, the serial 16-step chain (barrier-free, in-wave)
// interleaves the bulk GEMM k-blocks of chunk cc+1 (prefix k < 16cc is final);
// after the chain barrier, one final zero-padded k-block completes acc(cc+1).
__global__ __launch_bounds__(NT, 2)
void shield_fused(const float* __restrict__ preds,
                  const bf16_t* __restrict__ Mhi,
                  const float* __restrict__ Dv, const float* __restrict__ Bv,
                  float* __restrict__ out)
{
    __shared__ bf16_t Phi[RB * PKS];   // 33,280 B
    __shared__ float  S[RB * SJ];      // 66,048 B

    const int tid  = threadIdx.x;
    const int b0   = blockIdx.x * RB;
    const int lane = tid & 63;
    const int w    = tid >> 6;
    const int cq   = lane & 15;
    const int q    = lane >> 4;

    const int   rp0  = w * 4;
    const int   matL = (lane >> 1) & 1;
    const float sgn  = matL ? -1.0f : 1.0f;   // negated space: all reduces are max

    // ---- load preds -> Phi (each wave loads exactly its own phase-2 rows) ----
    {
        const int r = tid >> 4, seg = tid & 15;
        const float* prow = preds + (size_t)(b0 + r) * V + seg * 32;
        #pragma unroll
        for (int k = 0; k < 32; k += 4) {
            const float4 p4 = *(const float4*)(prow + k);
            const int n = seg * 32 + k;
            Phi[r * PKS + n + 0] = (bf16_t)p4.x;
            Phi[r * PKS + n + 1] = (bf16_t)p4.y;
            Phi[r * PKS + n + 2] = (bf16_t)p4.z;
            Phi[r * PKS + n + 3] = (bf16_t)p4.w;
        }
    }

    int tJ[4];
    #pragma unroll
    for (int tt = 0; tt < 4; ++tt) tJ[tt] = ((4 * w + tt) << 4) + cq;
    const int aoff0 = cq * PKS + 8 * q;
    const int aoff1 = (16 + cq) * PKS + 8 * q;

    // acc(0) = bias(0) only (chunk 0 references only the bias column)
    f32x4 acc[2][4];
    #pragma unroll
    for (int tt = 0; tt < 4; ++tt) {
        const float b = Bv[tJ[tt]];
        const f32x4 bv = {b, b, b, b};
        acc[0][tt] = bv;
        acc[1][tt] = bv;
    }

    #pragma unroll 1
    for (int cc = 0; cc < NCHUNKS; ++cc) {
        const int v0 = cc * 16;
        // ---- dump completed acc(cc) -> S ----
        #pragma unroll
        for (int tt = 0; tt < 4; ++tt)
            #pragma unroll
            for (int reg = 0; reg < 4; ++reg) {
                S[(4 * q + reg) * SJ + tJ[tt]]      = acc[0][tt][reg];
                S[(16 + 4 * q + reg) * SJ + tJ[tt]] = acc[1][tt][reg];
            }

        const int  ccn  = cc + 1;
        const bool hasN = ccn < NCHUNKS;
        const int  nkbN = hasN ? ((ccn + 1) >> 1) : 0;
        const bf16_t* phN = Mhi + 16384ull * (size_t)((ccn * ccn) / 4)
                          + (size_t)lane * 8 + (size_t)(4 * w) * 512;

        __syncthreads();   // S visible (and prior Phi writes)

        // ---- load s2 from S (negated space for mat=1) ----
        float s2[8][4];
        #pragma unroll
        for (int r = 0; r < 4; ++r) {
            const float4 x0 = *(const float4*)(&S[(rp0 + r) * SJ + 8 * lane]);
            const float4 x1 = *(const float4*)(&S[(rp0 + r) * SJ + 8 * lane + 4]);
            s2[0][r] = sgn * x0.x; s2[1][r] = sgn * x0.y;
            s2[2][r] = sgn * x0.z; s2[3][r] = sgn * x0.w;
            s2[4][r] = sgn * x1.x; s2[5][r] = sgn * x1.y;
            s2[6][r] = sgn * x1.z; s2[7][r] = sgn * x1.w;
        }

        // ---- init acc(ccn) with exact bias ----
        if (hasN) {
            #pragma unroll
            for (int tt = 0; tt < 4; ++tt) {
                const float b = Bv[(ccn << 9) + tJ[tt]];
                const f32x4 bv = {b, b, b, b};
                acc[0][tt] = bv;
                acc[1][tt] = bv;
            }
        }

        // preload dv/po for vl = 0
        float dv[8], po[4];
        {
            const float* dp = Dv + ((size_t)v0 << 9) + 8 * lane;
            const float4 d0 = *(const float4*)(dp);
            const float4 d1 = *(const float4*)(dp + 4);
            dv[0]=d0.x; dv[1]=d0.y; dv[2]=d0.z; dv[3]=d0.w;
            dv[4]=d1.x; dv[5]=d1.y; dv[6]=d1.z; dv[7]=d1.w;
            #pragma unroll
            for (int r = 0; r < 4; ++r)
                po[r] = (float)Phi[(rp0 + r) * PKS + v0];
        }

        // ---- 16-step serial chain, with next chunk's bulk GEMM interleaved ----
        #pragma unroll
        for (int vl = 0; vl < KCH; ++vl) {
            const int vcur = v0 + vl;
            const bool doKb = hasN && (vl < nkbN - 1);   // k-block vl: k < 16cc, final

            // issue bulk-GEMM loads early (consumed after the chain work below)
            bf16x8 fa0, fa1, fb0, fb1, fb2, fb3;
            if (doKb) {
                const int k0 = vl * 32;
                fa0 = *(const bf16x8*)(Phi + aoff0 + k0);
                fa1 = *(const bf16x8*)(Phi + aoff1 + k0);
                const bf16_t* pb = phN + (size_t)(vl * 32) * 512;
                fb0 = *(const bf16x8*)(pb);
                fb1 = *(const bf16x8*)(pb + 512);
                fb2 = *(const bf16x8*)(pb + 1024);
                fb3 = *(const bf16x8*)(pb + 1536);
            }

            // prefetch next step's dv/po (off the dependency chain)
            float dvN[8], poN[4];
            if (vl + 1 < KCH) {
                const float* dp = Dv + ((size_t)(vcur + 1) << 9) + 8 * lane;
                const float4 d0 = *(const float4*)(dp);
                const float4 d1 = *(const float4*)(dp + 4);
                dvN[0]=d0.x; dvN[1]=d0.y; dvN[2]=d0.z; dvN[3]=d0.w;
                dvN[4]=d1.x; dvN[5]=d1.y; dvN[6]=d1.z; dvN[7]=d1.w;
                #pragma unroll
                for (int r = 0; r < 4; ++r)
                    poN[r] = (float)Phi[(rp0 + r) * PKS + vcur + 1];
            }

            // in-lane reduce 8 -> 1, then merge ch partner (xor 1)
            float red[4];
            #pragma unroll
            for (int r = 0; r < 4; ++r) {
                const float x = fmaxf(fmaxf(s2[0][r], s2[1][r]), fmaxf(s2[2][r], s2[3][r]));
                const float y = fmaxf(fmaxf(s2[4][r], s2[5][r]), fmaxf(s2[6][r], s2[7][r]));
                red[r] = fmaxf(fmaxf(x, y), __shfl_xor(fmaxf(x, y), 1, 64));
            }
            // owner lanes: 4*vl holds lower, 4*vl+2 holds -upper (constant lanes)
            float pc[4];
            #pragma unroll
            for (int r = 0; r < 4; ++r) {
                const float lw  = __shfl(red[r], 4 * vl, 64);
                const float nup = __shfl(red[r], 4 * vl + 2, 64);
                pc[r] = fminf(fmaxf(po[r], lw), -nup);
            }
            if (lane == 4 * vl) {   // owner writes corrected value (bf16)
                #pragma unroll
                for (int r = 0; r < 4; ++r)
                    Phi[(rp0 + r) * PKS + vcur] = (bf16_t)pc[r];
            }
            // exact fp32 rank-1 update (masked zeros -> no-op for finished slots)
            #pragma unroll
            for (int jj = 0; jj < 8; ++jj) {
                const float sdv = sgn * dv[jj];
                #pragma unroll
                for (int r = 0; r < 4; ++r)
                    s2[jj][r] = fmaf(sdv, pc[r], s2[jj][r]);
            }

            // bulk GEMM MFMAs (matrix pipe; loads have had the whole chain to land)
            if (doKb) {
                acc[0][0] = mfma16(fa0, fb0, acc[0][0]);
                acc[1][0] = mfma16(fa1, fb0, acc[1][0]);
                acc[0][1] = mfma16(fa0, fb1, acc[0][1]);
                acc[1][1] = mfma16(fa1, fb1, acc[1][1]);
                acc[0][2] = mfma16(fa0, fb2, acc[0][2]);
                acc[1][2] = mfma16(fa1, fb2, acc[1][2]);
                acc[0][3] = mfma16(fa0, fb3, acc[0][3]);
                acc[1][3] = mfma16(fa1, fb3, acc[1][3]);
            }

            // rotate prefetched values (unrolled -> pure renaming)
            if (vl + 1 < KCH) {
                #pragma unroll
                for (int jj = 0; jj < 8; ++jj) dv[jj] = dvN[jj];
                #pragma unroll
                for (int r = 0; r < 4; ++r) po[r] = poN[r];
            }
        }

        __syncthreads();   // fresh Phi columns [16cc, 16cc+16) visible to all waves

        // ---- final k-block of chunk ccn (includes freshly corrected columns;
        //      zero-padded B makes out-of-range columns exact no-ops) ----
        if (hasN) {
            const int k0 = (nkbN - 1) * 32;
            const bf16x8 fa0 = *(const bf16x8*)(Phi + aoff0 + k0);
            const bf16x8 fa1 = *(const bf16x8*)(Phi + aoff1 + k0);
            const bf16_t* pb = phN + (size_t)k0 * 512;
            const bf16x8 fb0 = *(const bf16x8*)(pb);
            const bf16x8 fb1 = *(const bf16x8*)(pb + 512);
            const bf16x8 fb2 = *(const bf16x8*)(pb + 1024);
            const bf16x8 fb3 = *(const bf16x8*)(pb + 1536);
            acc[0][0] = mfma16(fa0, fb0, acc[0][0]);
            acc[1][0] = mfma16(fa1, fb0, acc[1][0]);
            acc[0][1] = mfma16(fa0, fb1, acc[0][1]);
            acc[1][1] = mfma16(fa1, fb1, acc[1][1]);
            acc[0][2] = mfma16(fa0, fb2, acc[0][2]);
            acc[1][2] = mfma16(fa1, fb2, acc[1][2]);
            acc[0][3] = mfma16(fa0, fb3, acc[0][3]);
            acc[1][3] = mfma16(fa1, fb3, acc[1][3]);
        }
    }

    // ---- epilogue (last barrier in loop guarantees Phi complete) ----
    {
        const int r = tid >> 4, seg = tid & 15;
        float* orow = out + (size_t)(b0 + r) * V + seg * 32;
        #pragma unroll
        for (int k = 0; k < 32; k += 4) {
            const int n = seg * 32 + k;
            float4 o;
            o.x = (float)Phi[r * PKS + n + 0];
            o.y = (float)Phi[r * PKS + n + 1];
            o.z = (float)Phi[r * PKS + n + 2];
            o.w = (float)Phi[r * PKS + n + 3];
            *(float4*)(orow + k) = o;
        }
    }
}

extern "C" void kernel_launch(void* const* d_in, const int* in_sizes, int n_in,
                              void* d_out, int out_size, void* d_ws, size_t ws_size,
                              hipStream_t stream) {
    const float* preds = (const float*)d_in[0];
    const float* pos   = (const float*)d_in[1];
    const float* neg   = (const float*)d_in[2];
    float* o = (float*)d_out;
    char* base = (char*)d_ws;
    bf16_t* Mhi = (bf16_t*)base;
    float*  Dv  = (float*)(base + DV_OFF);
    float*  Bv  = (float*)(base + BV_OFF);
    repack_m<<<dim3(31, 16), 256, 0, stream>>>(pos, neg, Mhi);
    repack_dv<<<dim3(1088), 256, 0, stream>>>(pos, neg, Dv, Bv);
    shield_fused<<<dim3(BATCH / RB), NT, 0, stream>>>(preds, Mhi, Dv, Bv, o);
}